// Round 1
// baseline (1930.790 us; speedup 1.0000x reference)
//
#include <hip/hip_runtime.h>
#include <math.h>

#define BB 4
#define CC 64
#define HH 128
#define WW 128
#define HW (HH*WW)
#define HP (HH+2)
#define WP (WW+2)
#define NPT 9

// ---------------------------------------------------------------------------
// Offset/mask conv: om[b][ch][i][j], ch in [0,27): 0..17 raw offsets (x then y),
// 18..26 sigmoid(mask). 3x3 conv, pad 1, over 64 input channels.
// ---------------------------------------------------------------------------
__global__ __launch_bounds__(256) void offc_kernel(
    const float* __restrict__ x,
    const float* __restrict__ w_p, const float* __restrict__ b_p,
    const float* __restrict__ w_m, const float* __restrict__ b_m,
    float* __restrict__ om)
{
    int idx = blockIdx.x * blockDim.x + threadIdx.x;
    const int total = BB * 27 * HW;
    if (idx >= total) return;
    int j  = idx % WW;
    int i  = (idx / WW) % HH;
    int ch = (idx / HW) % 27;
    int b  = idx / (27 * HW);

    const float* wgt;
    float bias;
    if (ch < 18) { wgt = w_p + ch * CC * 9;        bias = b_p[ch]; }
    else         { wgt = w_m + (ch - 18) * CC * 9; bias = b_m[ch - 18]; }

    float acc = bias;
    const float* xb = x + (size_t)b * CC * HW;
    for (int c = 0; c < CC; ++c) {
        const float* xc = xb + c * HW;
        const float* wc = wgt + c * 9;
        #pragma unroll
        for (int ki = 0; ki < 3; ++ki) {
            int ii = i + ki - 1;
            if (ii < 0 || ii >= HH) continue;
            #pragma unroll
            for (int kj = 0; kj < 3; ++kj) {
                int jj = j + kj - 1;
                if (jj < 0 || jj >= WW) continue;
                acc = fmaf(wc[ki * 3 + kj], xc[ii * WW + jj], acc);
            }
        }
    }
    if (ch >= 18) acc = 1.0f / (1.0f + expf(-acc));
    om[idx] = acc;
}

// ---------------------------------------------------------------------------
// Weight transpose: w_c (oc, c, ki, kj) -> wt[n][c4][oc][ci] (float4 of 4 c's
// per lane), n = ki*3+kj, c = c4*4+ci.  Total 9*16*64*4 = 36864 floats.
// ---------------------------------------------------------------------------
__global__ void wtr_kernel(const float* __restrict__ w_c, float* __restrict__ wt)
{
    int idx = blockIdx.x * blockDim.x + threadIdx.x;
    if (idx >= 9 * 16 * 64 * 4) return;
    int ci = idx & 3;
    int oc = (idx >> 2) & 63;
    int c4 = (idx >> 8) & 15;
    int n  = idx >> 12;
    int c  = c4 * 4 + ci;
    wt[idx] = w_c[(oc * CC + c) * 9 + n];
}

// ---------------------------------------------------------------------------
// Deformable sampling + modulation + 64x576 contraction, fused relu/residual.
// Block = 256 threads = 4 waves; one wave per output pixel.
//   Phase A (lane = input channel c): bilinear sample * mask -> LDS
//   Phase B (lane = output channel oc): acc += sum_c wt[n][c][oc] * s[c]
// ---------------------------------------------------------------------------
__device__ __forceinline__ float sample_pad(const float* __restrict__ xc, int a, int bb2)
{
    // (a, bb2) are coords in the zero-padded (HP x WP) frame
    if (a >= 1 && a <= HH && bb2 >= 1 && bb2 <= WW)
        return xc[(a - 1) * WW + (bb2 - 1)];
    return 0.0f;
}

__global__ __launch_bounds__(256) void deform_kernel(
    const float* __restrict__ xin,   // (B,64,H,W) feature being sampled
    const float* __restrict__ om,    // (B,27,H,W)
    const float* __restrict__ wt,    // [9][16][64][4]
    const float* __restrict__ res,   // residual (or nullptr)
    float* __restrict__ out,         // (B,64,H,W)
    int do_relu)
{
    __shared__ float s_lds[4][64];
    const int wave = threadIdx.x >> 6;
    const int lane = threadIdx.x & 63;
    const int pix  = blockIdx.x * 4 + wave;   // grid sized exactly: B*H*W/4 blocks
    const int j = pix % WW;
    const int i = (pix / WW) % HH;
    const int b = pix / HW;
    const int pos = i * WW + j;

    const float* xb  = xin + ((size_t)b * CC + lane) * HW;  // channel = lane
    const float* omb = om + (size_t)b * 27 * HW;

    float acc = 0.0f;
    for (int n = 0; n < NPT; ++n) {
        float offx = omb[n * HW + pos];
        float offy = omb[(9 + n) * HW + pos];
        float mval = omb[(18 + n) * HW + pos];
        float px = (float)(i + (n / 3)) + offx;   // (i+1) + (n/3 - 1)
        float py = (float)(j + (n % 3)) + offy;   // (j+1) + (n%3 - 1)
        float fx = floorf(px), fy = floorf(py);
        float qltx = fminf(fmaxf(fx,        0.0f), (float)(HP - 1));
        float qlty = fminf(fmaxf(fy,        0.0f), (float)(WP - 1));
        float qrbx = fminf(fmaxf(fx + 1.0f, 0.0f), (float)(HP - 1));
        float qrby = fminf(fmaxf(fy + 1.0f, 0.0f), (float)(WP - 1));
        float pxc  = fminf(fmaxf(px,        0.0f), (float)(HP - 1));
        float pyc  = fminf(fmaxf(py,        0.0f), (float)(WP - 1));
        float glt = (1.0f + (qltx - pxc)) * (1.0f + (qlty - pyc));
        float grb = (1.0f - (qrbx - pxc)) * (1.0f - (qrby - pyc));
        float glb = (1.0f + (qltx - pxc)) * (1.0f - (qrby - pyc));
        float grt = (1.0f - (qrbx - pxc)) * (1.0f + (qlty - pyc));
        int ltx = (int)qltx, lty = (int)qlty, rbx = (int)qrbx, rby = (int)qrby;

        float vlt = sample_pad(xb, ltx, lty);
        float vrb = sample_pad(xb, rbx, rby);
        float vlb = sample_pad(xb, ltx, rby);
        float vrt = sample_pad(xb, rbx, lty);
        float sv = (glt * vlt + grb * vrb + glb * vlb + grt * vrt) * mval;

        __syncthreads();                    // prev-n LDS reads done
        s_lds[wave][lane] = sv;
        __syncthreads();                    // writes visible

        const float4* wn4 = (const float4*)(wt + n * 4096);  // [c4][oc][4]
        #pragma unroll
        for (int c4 = 0; c4 < 16; ++c4) {
            float4 s4 = *(const float4*)&s_lds[wave][c4 * 4];
            float4 w4 = wn4[c4 * 64 + lane];                 // lane = oc
            acc = fmaf(w4.x, s4.x, acc);
            acc = fmaf(w4.y, s4.y, acc);
            acc = fmaf(w4.z, s4.z, acc);
            acc = fmaf(w4.w, s4.w, acc);
        }
    }

    if (do_relu) acc = fmaxf(acc, 0.0f);
    size_t oidx = ((size_t)b * CC + lane) * HW + pos;
    if (res) acc += res[oidx];
    out[oidx] = acc;
}

// ---------------------------------------------------------------------------
extern "C" void kernel_launch(void* const* d_in, const int* in_sizes, int n_in,
                              void* d_out, int out_size, void* d_ws, size_t ws_size,
                              hipStream_t stream)
{
    const float* x      = (const float*)d_in[0];
    const float* d1_w_p = (const float*)d_in[1];
    const float* d1_b_p = (const float*)d_in[2];
    const float* d1_w_m = (const float*)d_in[3];
    const float* d1_b_m = (const float*)d_in[4];
    const float* d1_w_c = (const float*)d_in[5];
    const float* d2_w_p = (const float*)d_in[6];
    const float* d2_b_p = (const float*)d_in[7];
    const float* d2_w_m = (const float*)d_in[8];
    const float* d2_b_m = (const float*)d_in[9];
    const float* d2_w_c = (const float*)d_in[10];
    float* out = (float*)d_out;

    char* ws = (char*)d_ws;
    float* om = (float*)ws;                               // 4*27*16384*4 = 7,077,888 B
    float* y1 = (float*)(ws + 7077888);                   // 4*64*16384*4 = 16,777,216 B
    float* wt = (float*)(ws + 7077888 + 16777216);        // 36864*4 = 147,456 B

    const int offc_total = BB * 27 * HW;
    const int offc_blocks = (offc_total + 255) / 256;
    const int wtr_blocks = (36864 + 255) / 256;
    const int def_blocks = BB * HW / 4;

    // ---- layer 1 ----
    wtr_kernel<<<wtr_blocks, 256, 0, stream>>>(d1_w_c, wt);
    offc_kernel<<<offc_blocks, 256, 0, stream>>>(x, d1_w_p, d1_b_p, d1_w_m, d1_b_m, om);
    deform_kernel<<<def_blocks, 256, 0, stream>>>(x, om, wt, nullptr, y1, 1);

    // ---- layer 2 ----
    wtr_kernel<<<wtr_blocks, 256, 0, stream>>>(d2_w_c, wt);
    offc_kernel<<<offc_blocks, 256, 0, stream>>>(y1, d2_w_p, d2_b_p, d2_w_m, d2_b_m, om);
    deform_kernel<<<def_blocks, 256, 0, stream>>>(y1, om, wt, x, out, 0);
}

// Round 2
// 395.101 us; speedup vs baseline: 4.8868x; 4.8868x over previous
//
#include <hip/hip_runtime.h>
#include <math.h>

#define BB 4
#define CC 64
#define HH 128
#define WW 128
#define HWSZ 16384
#define PADW 130
#define PADSLAB (PADW*PADW*64)     // floats per batch in padded NHWC

// swizzled LDS index for a [64 px][64 c] fp32 tile: conflict-free for
// c-major writes (lane=c) AND px-major b128 reads (lane=px).
__device__ __forceinline__ int swzidx(int px, int c) {
    return px * 64 + ((((c >> 2) ^ (px & 15)) << 2) | (c & 3));
}

// ---------------------------------------------------------------------------
// NCHW -> padded NHWC transpose. lane = channel, coalesced 256B writes;
// reads amortize 64B lines across 16 consecutive p iterations via L1.
// ---------------------------------------------------------------------------
__global__ __launch_bounds__(256, 2) void nchw2nhwc(
    const float* __restrict__ x, float* __restrict__ xt)
{
    int c  = threadIdx.x & 63;
    int wv = __builtin_amdgcn_readfirstlane(threadIdx.x >> 6);
    int pix0 = blockIdx.x * 256 + wv * 64;
    int bb = pix0 >> 14;
    const float* xp = x + ((size_t)(bb * 64 + c)) * HWSZ;
    #pragma unroll 8
    for (int p = 0; p < 64; ++p) {
        int pxi = (pix0 + p) & (HWSZ - 1);
        int i = pxi >> 7, j = pxi & 127;
        xt[((size_t)bb * PADSLAB) + ((i + 1) * PADW + (j + 1)) * 64 + c] = xp[pxi];
    }
}

// wd[(n*64+c)*64 + oc] = w_c[oc][c][n]
__global__ void prep_wd(const float* __restrict__ wc, float* __restrict__ wd)
{
    int idx = blockIdx.x * 256 + threadIdx.x;
    if (idx >= 36864) return;
    int oc = idx & 63, k = idx >> 6;
    int c = k & 63, n = k >> 6;
    wd[idx] = wc[(oc * 64 + c) * 9 + n];
}

// wo[(tap*64+c)*32 + ch] : ch<18 -> w_p, 18..26 -> w_m, 27..31 -> 0 pad
__global__ void prep_wo(const float* __restrict__ wp, const float* __restrict__ wm,
                        float* __restrict__ wo)
{
    int idx = blockIdx.x * 256 + threadIdx.x;
    if (idx >= 18432) return;
    int ch = idx & 31, k = idx >> 5;
    int c = k & 63, tap = k >> 6;
    float v = 0.f;
    if (ch < 18)      v = wp[(ch * 64 + c) * 9 + tap];
    else if (ch < 27) v = wm[((ch - 18) * 64 + c) * 9 + tap];
    wo[idx] = v;
}

// ---------------------------------------------------------------------------
// Offset/mask conv (27ch padded to 32). Block = 128 thr (2 waves), 64 px.
// Stage tap-tile to LDS (coalesced), then lane=px, SGPR-weight FMA loop.
// ---------------------------------------------------------------------------
__global__ __launch_bounds__(128, 2) void offc(
    const float* __restrict__ xt, const float* __restrict__ wo,
    const float* __restrict__ bp, const float* __restrict__ bm,
    float* __restrict__ om)
{
    __shared__ float S[4096];
    int t = threadIdx.x;
    int lane = t & 63;
    int wv = __builtin_amdgcn_readfirstlane(t >> 6);
    int ob = wv * 16;
    int pix0 = blockIdx.x * 64;
    int bb = pix0 >> 14, pxb = pix0 & (HWSZ - 1);

    float acc[16];
    #pragma unroll
    for (int i = 0; i < 16; ++i) {
        int ch = ob + i;
        acc[i] = (ch < 18) ? bp[ch] : (ch < 27 ? bm[ch - 18] : 0.f);
    }
    const float* xb = xt + (size_t)bb * PADSLAB;

    for (int tap = 0; tap < 9; ++tap) {
        int ti = tap / 3, tj = tap - ti * 3;
        #pragma unroll 4
        for (int p = 0; p < 32; ++p) {
            int pl = wv * 32 + p;
            int pxi = pxb + pl;
            int i = pxi >> 7, j = pxi & 127;
            S[swzidx(pl, lane)] = xb[((i + ti) * PADW + (j + tj)) * 64 + lane];
        }
        __syncthreads();
        const float* wn = wo + tap * 64 * 32;
        #pragma unroll
        for (int c4 = 0; c4 < 16; ++c4) {
            float4 s4 = *(const float4*)&S[lane * 64 + (((c4 ^ (lane & 15))) << 2)];
            const float* w0 = wn + (c4 * 4 + 0) * 32 + ob;
            const float* w1 = wn + (c4 * 4 + 1) * 32 + ob;
            const float* w2 = wn + (c4 * 4 + 2) * 32 + ob;
            const float* w3 = wn + (c4 * 4 + 3) * 32 + ob;
            #pragma unroll
            for (int i = 0; i < 16; ++i) {
                acc[i] = fmaf(s4.x, w0[i], acc[i]);
                acc[i] = fmaf(s4.y, w1[i], acc[i]);
                acc[i] = fmaf(s4.z, w2[i], acc[i]);
                acc[i] = fmaf(s4.w, w3[i], acc[i]);
            }
        }
        __syncthreads();
    }

    int pxi = pxb + lane;
    #pragma unroll
    for (int i = 0; i < 16; ++i) {
        int ch = ob + i;
        if (ch >= 27) break;               // wave-uniform
        float v = acc[i];
        if (ch >= 18) v = 1.f / (1.f + __expf(-v));
        om[((size_t)(bb * 27 + ch)) * HWSZ + pxi] = v;
    }
}

// ---------------------------------------------------------------------------
// Deformable sampling + 64x576 contraction. Block = 256 thr (4 waves), 64 px.
// Phase A: lane=c coalesced bilinear sampling from padded NHWC -> swizzled LDS.
// Phase B: lane=px, wave owns 16 oc, weights via wave-uniform s_loads.
// mode 1: relu + write padded-NHWC y1 (LDS transpose epilogue)
// mode 0: residual add + write NCHW out
// ---------------------------------------------------------------------------
__global__ __launch_bounds__(256, 2) void deform(
    const float* __restrict__ xt, const float* __restrict__ om,
    const float* __restrict__ wd, const float* __restrict__ xres,
    float* __restrict__ outn, float* __restrict__ y1t, int mode)
{
    __shared__ float S[4096];
    int t = threadIdx.x;
    int lane = t & 63;
    int wv = __builtin_amdgcn_readfirstlane(t >> 6);
    int ob = wv * 16;
    int pix0 = blockIdx.x * 64;
    int bb = pix0 >> 14, pxb = pix0 & (HWSZ - 1);

    float acc[16];
    #pragma unroll
    for (int i = 0; i < 16; ++i) acc[i] = 0.f;

    const float* xb  = xt + (size_t)bb * PADSLAB;
    const float* omb = om + (size_t)bb * 27 * HWSZ;

    for (int n = 0; n < 9; ++n) {
        int di = n / 3, dj = n - di * 3;
        #pragma unroll 4
        for (int p = 0; p < 16; ++p) {
            int pl = wv * 16 + p;
            int pxi = pxb + pl;
            int i = pxi >> 7, j = pxi & 127;
            float offx = omb[n * HWSZ + pxi];
            float offy = omb[(9 + n) * HWSZ + pxi];
            float mval = omb[(18 + n) * HWSZ + pxi];
            float px = (float)(i + di) + offx;
            float py = (float)(j + dj) + offy;
            float fx = floorf(px), fy = floorf(py);
            float qltx = fminf(fmaxf(fx,       0.f), 129.f);
            float qlty = fminf(fmaxf(fy,       0.f), 129.f);
            float qrbx = fminf(fmaxf(fx + 1.f, 0.f), 129.f);
            float qrby = fminf(fmaxf(fy + 1.f, 0.f), 129.f);
            float pxc  = fminf(fmaxf(px,       0.f), 129.f);
            float pyc  = fminf(fmaxf(py,       0.f), 129.f);
            float glt = (1.f + (qltx - pxc)) * (1.f + (qlty - pyc));
            float grb = (1.f - (qrbx - pxc)) * (1.f - (qrby - pyc));
            float glb = (1.f + (qltx - pxc)) * (1.f - (qrby - pyc));
            float grt = (1.f - (qrbx - pxc)) * (1.f + (qlty - pyc));
            int ltx = (int)qltx, lty = (int)qlty, rbx = (int)qrbx, rby = (int)qrby;
            float vlt = xb[(ltx * PADW + lty) * 64 + lane];
            float vrb = xb[(rbx * PADW + rby) * 64 + lane];
            float vlb = xb[(ltx * PADW + rby) * 64 + lane];
            float vrt = xb[(rbx * PADW + lty) * 64 + lane];
            float sv = (glt * vlt + grb * vrb + glb * vlb + grt * vrt) * mval;
            S[swzidx(pl, lane)] = sv;
        }
        __syncthreads();
        const float* wn = wd + n * 64 * 64;
        #pragma unroll
        for (int c4 = 0; c4 < 16; ++c4) {
            float4 s4 = *(const float4*)&S[lane * 64 + (((c4 ^ (lane & 15))) << 2)];
            const float* w0 = wn + (c4 * 4 + 0) * 64 + ob;
            const float* w1 = wn + (c4 * 4 + 1) * 64 + ob;
            const float* w2 = wn + (c4 * 4 + 2) * 64 + ob;
            const float* w3 = wn + (c4 * 4 + 3) * 64 + ob;
            #pragma unroll
            for (int i = 0; i < 16; ++i) {
                acc[i] = fmaf(s4.x, w0[i], acc[i]);
                acc[i] = fmaf(s4.y, w1[i], acc[i]);
                acc[i] = fmaf(s4.z, w2[i], acc[i]);
                acc[i] = fmaf(s4.w, w3[i], acc[i]);
            }
        }
        __syncthreads();
    }

    if (mode == 1) {
        // relu, transpose through LDS, write padded-NHWC y1 (coalesced)
        #pragma unroll
        for (int i = 0; i < 16; ++i) {
            int oc = ob + i;
            S[swzidx(lane, oc)] = fmaxf(acc[i], 0.f);
        }
        __syncthreads();
        int px = t >> 2, c0 = (t & 3) * 16;
        int pxi = pxb + px;
        int i = pxi >> 7, j = pxi & 127;
        float* dst = y1t + ((size_t)bb * PADSLAB) + ((i + 1) * PADW + (j + 1)) * 64 + c0;
        #pragma unroll
        for (int q = 0; q < 4; ++q) {
            int c4 = (c0 >> 2) + q;
            float4 v = *(const float4*)&S[px * 64 + ((c4 ^ (px & 15)) << 2)];
            ((float4*)dst)[q] = v;
        }
    } else {
        int pxi = pxb + lane;
        #pragma unroll
        for (int i = 0; i < 16; ++i) {
            int oc = ob + i;
            size_t o = ((size_t)(bb * 64 + oc)) * HWSZ + pxi;
            outn[o] = acc[i] + xres[o];
        }
    }
}

// ---------------------------------------------------------------------------
extern "C" void kernel_launch(void* const* d_in, const int* in_sizes, int n_in,
                              void* d_out, int out_size, void* d_ws, size_t ws_size,
                              hipStream_t stream)
{
    const float* x      = (const float*)d_in[0];
    const float* d1_w_p = (const float*)d_in[1];
    const float* d1_b_p = (const float*)d_in[2];
    const float* d1_w_m = (const float*)d_in[3];
    const float* d1_b_m = (const float*)d_in[4];
    const float* d1_w_c = (const float*)d_in[5];
    const float* d2_w_p = (const float*)d_in[6];
    const float* d2_b_p = (const float*)d_in[7];
    const float* d2_w_m = (const float*)d_in[8];
    const float* d2_b_m = (const float*)d_in[9];
    const float* d2_w_c = (const float*)d_in[10];
    float* out = (float*)d_out;

    char* ws = (char*)d_ws;
    float* om  = (float*)(ws);                 //  7,077,888 B  (B,27,H,W)
    float* xt  = (float*)(ws + 7077888);       // 17,305,600 B  padded NHWC x
    float* y1t = (float*)(ws + 24383488);      // 17,305,600 B  padded NHWC y1
    float* wd  = (float*)(ws + 41689088);      //    147,456 B  [576][64]
    float* wo  = (float*)(ws + 41836544);      //     73,728 B  [576][32]

    hipMemsetAsync(xt,  0, 17305600, stream);
    hipMemsetAsync(y1t, 0, 17305600, stream);
    nchw2nhwc<<<256, 256, 0, stream>>>(x, xt);

    // ---- layer 1 ----
    prep_wd<<<144, 256, 0, stream>>>(d1_w_c, wd);
    prep_wo<<<72, 256, 0, stream>>>(d1_w_p, d1_w_m, wo);
    offc<<<1024, 128, 0, stream>>>(xt, wo, d1_b_p, d1_b_m, om);
    deform<<<1024, 256, 0, stream>>>(xt, om, wd, nullptr, nullptr, y1t, 1);

    // ---- layer 2 ----
    prep_wd<<<144, 256, 0, stream>>>(d2_w_c, wd);
    prep_wo<<<72, 256, 0, stream>>>(d2_w_p, d2_w_m, wo);
    offc<<<1024, 128, 0, stream>>>(y1t, wo, d2_b_p, d2_b_m, om);
    deform<<<1024, 256, 0, stream>>>(y1t, om, wd, x, out, nullptr, 0);
}

// Round 3
// 142.608 us; speedup vs baseline: 13.5392x; 2.7705x over previous
//
#include <hip/hip_runtime.h>
#include <hip/hip_bf16.h>
#include <math.h>

typedef __attribute__((ext_vector_type(8))) short short8;
typedef __attribute__((ext_vector_type(4))) float f32x4;
typedef unsigned int uint;
typedef unsigned short ushort;

#define HWSZ 16384
#define PADW 130
#define SLAB (PADW*PADW*64)   // elems per batch, padded NHWC

__device__ __forceinline__ ushort f2bf(float f) {
    union { __hip_bfloat16 h; ushort u; } cv;
    cv.h = __float2bfloat16(f);
    return cv.u;
}

// ---------------------------------------------------------------------------
// NCHW fp32 -> padded NHWC bf16
// ---------------------------------------------------------------------------
__global__ __launch_bounds__(256, 2) void nchw2nhwc(
    const float* __restrict__ x, ushort* __restrict__ xt)
{
    int c  = threadIdx.x & 63;
    int wv = threadIdx.x >> 6;
    int pix0 = blockIdx.x * 256 + wv * 64;
    int bb = pix0 >> 14;
    const float* xp = x + ((size_t)(bb * 64 + c)) * HWSZ;
    ushort* xb = xt + (size_t)bb * SLAB;
    #pragma unroll 8
    for (int p = 0; p < 64; ++p) {
        int pxi = (pix0 + p) & (HWSZ - 1);
        int i = pxi >> 7, j = pxi & 127;
        xb[((i + 1) * PADW + (j + 1)) * 64 + c] = f2bf(xp[pxi]);
    }
}

// ---------------------------------------------------------------------------
// Weight prep, fragment-major bf16.
// wdf[((tap*2+kc)*4+nt)*512 + l*8 + j] = w_c[oc][c][tap],
//   c = kc*32 + (l>>4)*8 + j, oc = nt*16 + (l&15)
// ---------------------------------------------------------------------------
__global__ void prep_wdf(const float* __restrict__ wc, ushort* __restrict__ wdf)
{
    int idx = blockIdx.x * 256 + threadIdx.x;
    if (idx >= 36864) return;
    int j = idx & 7, l = (idx >> 3) & 63;
    int nt = (idx >> 9) & 3, kc = (idx >> 11) & 1, tap = idx >> 12;
    int c  = kc * 32 + (l >> 4) * 8 + j;
    int oc = nt * 16 + (l & 15);
    wdf[idx] = f2bf(wc[(oc * 64 + c) * 9 + tap]);
}

// wof: N=32 (27 padded): ch = nt*16 + (l&15); nt in {0,1}
__global__ void prep_wof(const float* __restrict__ wp, const float* __restrict__ wm,
                         ushort* __restrict__ wof)
{
    int idx = blockIdx.x * 256 + threadIdx.x;
    if (idx >= 18432) return;
    int j = idx & 7, l = (idx >> 3) & 63;
    int nt = (idx >> 9) & 1, kc = (idx >> 10) & 1, tap = idx >> 11;
    int c  = kc * 32 + (l >> 4) * 8 + j;
    int ch = nt * 16 + (l & 15);
    float v = 0.f;
    if (ch < 18)      v = wp[(ch * 64 + c) * 9 + tap];
    else if (ch < 27) v = wm[((ch - 18) * 64 + c) * 9 + tap];
    wof[idx] = f2bf(v);
}

// ---------------------------------------------------------------------------
// Offset/mask conv via MFMA. Block 256 thr / 4 waves / 64 px (one half-row).
// Stage [3][66][64ch] bf16 tile (XOR-swizzled via pre-swizzled source), then
// K = 9 taps x 64 c of 16x16x32 MFMA, N=32.
// ---------------------------------------------------------------------------
__global__ __launch_bounds__(256, 4) void offc(
    const ushort* __restrict__ xt, const ushort* __restrict__ wof,
    const float* __restrict__ bp, const float* __restrict__ bm,
    float* __restrict__ om)
{
    __shared__ __align__(16) char sm[25344];
    int t = threadIdx.x, l = t & 63, wv = t >> 6;
    int pix0 = blockIdx.x * 64;
    int bb = pix0 >> 14, pxb = pix0 & (HWSZ - 1);
    int i = pxb >> 7, j0 = pxb & 127;
    const ushort* xb = xt + (size_t)bb * SLAB;

    // stage: Xs[ti][r][slot s holds source chunk s ^ (r&7)]
    for (int q = t; q < 1584; q += 256) {
        int s = q & 7, rt = q >> 3;
        int r66 = rt % 66, ti = rt / 66;
        int c0 = (s ^ (r66 & 7)) * 8;
        uint4 v = *(const uint4*)(xb + ((i + ti) * PADW + j0 + r66) * 64 + c0);
        *(uint4*)(sm + (ti * 66 + r66) * 128 + s * 16) = v;
    }
    __syncthreads();

    f32x4 acc[2];
    f32x4 zero = {0.f, 0.f, 0.f, 0.f};
    acc[0] = zero; acc[1] = zero;

    for (int tap = 0; tap < 9; ++tap) {
        int ti = tap / 3, tj = tap - ti * 3;
        int rloc = wv * 16 + (l & 15) + tj;
        #pragma unroll
        for (int kc = 0; kc < 2; ++kc) {
            short8 a = *(const short8*)(sm + (ti * 66 + rloc) * 128 +
                        ((((kc << 2) + (l >> 4)) ^ (rloc & 7)) << 4));
            #pragma unroll
            for (int nt = 0; nt < 2; ++nt) {
                short8 b = *(const short8*)(wof + (((tap * 2 + kc) * 2 + nt) * 64 + l) * 8);
                acc[nt] = __builtin_amdgcn_mfma_f32_16x16x32_bf16(a, b, acc[nt], 0, 0, 0);
            }
        }
    }
    __syncthreads();

    // transpose via LDS: T[ch][px ^ (ch&31)]
    float* T = (float*)sm;
    #pragma unroll
    for (int nt = 0; nt < 2; ++nt)
        #pragma unroll
        for (int r = 0; r < 4; ++r) {
            int ch  = nt * 16 + (l & 15);
            int pxl = wv * 16 + (l >> 4) * 4 + r;
            T[ch * 64 + (pxl ^ (ch & 31))] = acc[nt][r];
        }
    __syncthreads();

    int px = t & 63, g = t >> 6;
    for (int k = 0; k < 7; ++k) {
        int ch = g + k * 4;
        if (ch >= 27) break;                      // wave-uniform
        float v = T[ch * 64 + (px ^ (ch & 31))];
        v += (ch < 18) ? bp[ch] : bm[ch - 18];
        if (ch >= 18) v = 1.f / (1.f + __expf(-v));
        om[((size_t)(bb * 27 + ch)) * HWSZ + pxb + px] = v;
    }
}

// ---------------------------------------------------------------------------
// Deformable sampling + MFMA contraction. Block 256 thr / 4 waves / 64 px.
//  - coord pass: all (64px, 9tap) -> SoA LDS {int4 corner byte-offsets,
//    float4 bilinear weights * mask}
//  - per tap: gather (2 px per pass, dword = 2 channels/lane) -> swizzled
//    bf16 S tile; 16x16x32 MFMA, weights fragment-major from L2
//  - mode 1: relu -> padded NHWC bf16 y1t; mode 0: +residual -> NCHW fp32
// ---------------------------------------------------------------------------
#define CB 0
#define CG 9216
#define SOF 18432

__global__ __launch_bounds__(256, 4) void deform(
    const ushort* __restrict__ xt, const float* __restrict__ om,
    const ushort* __restrict__ wdf, const float* __restrict__ xres,
    float* __restrict__ outn, ushort* __restrict__ y1t, int mode)
{
    __shared__ __align__(16) char sm[26624];
    int t = threadIdx.x, l = t & 63, wv = t >> 6;
    int pix0 = blockIdx.x * 64;
    int bb = pix0 >> 14, pxb = pix0 & (HWSZ - 1);
    const float* omb = om + (size_t)bb * 27 * HWSZ;

    // ---- coord pass ----
    for (int it = t; it < 576; it += 256) {
        int px = it & 63, tap = it >> 6;
        int pxi = pxb + px;
        int i = pxi >> 7, j = pxi & 127;
        int di = tap / 3, dj = tap - di * 3;
        float offx = omb[tap * HWSZ + pxi];
        float offy = omb[(9 + tap) * HWSZ + pxi];
        float mv   = omb[(18 + tap) * HWSZ + pxi];
        float pxf = (float)(i + di) + offx;
        float pyf = (float)(j + dj) + offy;
        float fx = floorf(pxf), fy = floorf(pyf);
        float qltx = fminf(fmaxf(fx,       0.f), 129.f);
        float qlty = fminf(fmaxf(fy,       0.f), 129.f);
        float qrbx = fminf(fmaxf(fx + 1.f, 0.f), 129.f);
        float qrby = fminf(fmaxf(fy + 1.f, 0.f), 129.f);
        float pxc  = fminf(fmaxf(pxf,      0.f), 129.f);
        float pyc  = fminf(fmaxf(pyf,      0.f), 129.f);
        float glt = (1.f + (qltx - pxc)) * (1.f + (qlty - pyc));
        float grb = (1.f - (qrbx - pxc)) * (1.f - (qrby - pyc));
        float glb = (1.f + (qltx - pxc)) * (1.f - (qrby - pyc));
        float grt = (1.f - (qrbx - pxc)) * (1.f + (qlty - pyc));
        int ltx = (int)qltx, lty = (int)qlty, rbx = (int)qrbx, rby = (int)qrby;
        int4 bs;
        bs.x = (ltx * PADW + lty) * 128;
        bs.y = (rbx * PADW + rby) * 128;
        bs.z = (ltx * PADW + rby) * 128;
        bs.w = (rbx * PADW + lty) * 128;
        float4 gg;
        gg.x = glt * mv; gg.y = grb * mv; gg.z = glb * mv; gg.w = grt * mv;
        *(int4*)(sm + CB + (tap * 64 + px) * 16) = bs;
        *(float4*)(sm + CG + (tap * 64 + px) * 16) = gg;
    }
    __syncthreads();

    const char* xbb = (const char*)(xt + (size_t)bb * SLAB);
    f32x4 acc[4];
    f32x4 zero = {0.f, 0.f, 0.f, 0.f};
    #pragma unroll
    for (int nt = 0; nt < 4; ++nt) acc[nt] = zero;

    for (int n = 0; n < 9; ++n) {
        // ---- gather: 8 passes x 2 px, lane handles 2 channels ----
        #pragma unroll
        for (int pp = 0; pp < 8; ++pp) {
            int px = wv * 16 + pp * 2 + (l >> 5);
            int4  bs = *(const int4*)(sm + CB + (n * 64 + px) * 16);
            float4 g = *(const float4*)(sm + CG + (n * 64 + px) * 16);
            int c4b = (l & 31) << 2;
            uint dlt = *(const uint*)(xbb + bs.x + c4b);
            uint drb = *(const uint*)(xbb + bs.y + c4b);
            uint dlb = *(const uint*)(xbb + bs.z + c4b);
            uint drt = *(const uint*)(xbb + bs.w + c4b);
            float v0 = g.x * __uint_as_float(dlt << 16);
            float v1 = g.x * __uint_as_float(dlt & 0xffff0000u);
            v0 = fmaf(g.y, __uint_as_float(drb << 16),        v0);
            v1 = fmaf(g.y, __uint_as_float(drb & 0xffff0000u), v1);
            v0 = fmaf(g.z, __uint_as_float(dlb << 16),        v0);
            v1 = fmaf(g.z, __uint_as_float(dlb & 0xffff0000u), v1);
            v0 = fmaf(g.w, __uint_as_float(drt << 16),        v0);
            v1 = fmaf(g.w, __uint_as_float(drt & 0xffff0000u), v1);
            union { __hip_bfloat162 h; uint u; } cv;
            cv.h = __float22bfloat162_rn(make_float2(v0, v1));
            int c2 = l & 31;
            *(uint*)(sm + SOF + px * 128 + (((c2 >> 2) ^ (px & 7)) << 4) + ((c2 & 3) << 2)) = cv.u;
        }
        __syncthreads();

        // ---- MFMA: wave tile 16px x 64oc, K=64 ----
        int pxm = wv * 16 + (l & 15);
        #pragma unroll
        for (int kc = 0; kc < 2; ++kc) {
            short8 a = *(const short8*)(sm + SOF + pxm * 128 +
                        ((((kc << 2) + (l >> 4)) ^ (pxm & 7)) << 4));
            #pragma unroll
            for (int nt = 0; nt < 4; ++nt) {
                short8 b = *(const short8*)(wdf + (((n * 2 + kc) * 4 + nt) * 64 + l) * 8);
                acc[nt] = __builtin_amdgcn_mfma_f32_16x16x32_bf16(a, b, acc[nt], 0, 0, 0);
            }
        }
        __syncthreads();
    }

    // ---- epilogue: transpose via LDS (overlays coord buf) ----
    float* T = (float*)sm;
    #pragma unroll
    for (int nt = 0; nt < 4; ++nt)
        #pragma unroll
        for (int r = 0; r < 4; ++r) {
            int oc  = nt * 16 + (l & 15);
            int pxl = wv * 16 + (l >> 4) * 4 + r;
            T[oc * 64 + (pxl ^ (oc & 31))] = acc[nt][r];
        }
    __syncthreads();

    if (mode == 0) {
        int px = t & 63, g = t >> 6;
        #pragma unroll
        for (int k = 0; k < 16; ++k) {
            int oc = g * 16 + k;
            size_t o = ((size_t)(bb * 64 + oc)) * HWSZ + pxb + px;
            outn[o] = T[oc * 64 + (px ^ (oc & 31))] + xres[o];
        }
    } else {
        int px = t & 63, cg = t >> 6;
        int pxi = pxb + px;
        int i = pxi >> 7, j = pxi & 127;
        ushort* dst = y1t + (size_t)bb * SLAB + ((i + 1) * PADW + (j + 1)) * 64 + cg * 16;
        uint w[8];
        #pragma unroll
        for (int k2 = 0; k2 < 8; ++k2) {
            int oc0 = cg * 16 + k2 * 2;
            float a0 = fmaxf(T[oc0 * 64 + (px ^ (oc0 & 31))], 0.f);
            float a1 = fmaxf(T[(oc0 + 1) * 64 + (px ^ ((oc0 + 1) & 31))], 0.f);
            union { __hip_bfloat162 h; uint u; } cv;
            cv.h = __float22bfloat162_rn(make_float2(a0, a1));
            w[k2] = cv.u;
        }
        uint4 A = make_uint4(w[0], w[1], w[2], w[3]);
        uint4 Bv = make_uint4(w[4], w[5], w[6], w[7]);
        *(uint4*)dst = A;
        *(uint4*)(dst + 8) = Bv;
    }
}

// ---------------------------------------------------------------------------
extern "C" void kernel_launch(void* const* d_in, const int* in_sizes, int n_in,
                              void* d_out, int out_size, void* d_ws, size_t ws_size,
                              hipStream_t stream)
{
    const float* x      = (const float*)d_in[0];
    const float* d1_w_p = (const float*)d_in[1];
    const float* d1_b_p = (const float*)d_in[2];
    const float* d1_w_m = (const float*)d_in[3];
    const float* d1_b_m = (const float*)d_in[4];
    const float* d1_w_c = (const float*)d_in[5];
    const float* d2_w_p = (const float*)d_in[6];
    const float* d2_b_p = (const float*)d_in[7];
    const float* d2_w_m = (const float*)d_in[8];
    const float* d2_b_m = (const float*)d_in[9];
    const float* d2_w_c = (const float*)d_in[10];
    float* out = (float*)d_out;

    char* ws = (char*)d_ws;
    float*  om  = (float*)(ws);                    //  7,077,888 B  (B,27,H,W) fp32
    ushort* xt  = (ushort*)(ws + 7077888);         //  8,652,800 B  padded NHWC bf16 x
    ushort* y1t = (ushort*)(ws + 15730688);        //  8,652,800 B  padded NHWC bf16 y1
    ushort* wdf = (ushort*)(ws + 24383488);        //     73,728 B  frag-major deform w
    ushort* wof = (ushort*)(ws + 24457216);        //     36,864 B  frag-major offc w

    hipMemsetAsync(xt,  0, 8652800, stream);
    hipMemsetAsync(y1t, 0, 8652800, stream);
    nchw2nhwc<<<256, 256, 0, stream>>>(x, xt);

    // ---- layer 1 ----
    prep_wdf<<<144, 256, 0, stream>>>(d1_w_c, wdf);
    prep_wof<<<72, 256, 0, stream>>>(d1_w_p, d1_w_m, wof);
    offc<<<1024, 256, 0, stream>>>(xt, wof, d1_b_p, d1_b_m, om);
    deform<<<1024, 256, 0, stream>>>(xt, om, wdf, nullptr, nullptr, y1t, 1);

    // ---- layer 2 ----
    prep_wdf<<<144, 256, 0, stream>>>(d2_w_c, wdf);
    prep_wof<<<72, 256, 0, stream>>>(d2_w_p, d2_w_m, wof);
    offc<<<1024, 256, 0, stream>>>(y1t, wof, d2_b_p, d2_b_m, om);
    deform<<<1024, 256, 0, stream>>>(y1t, om, wdf, x, out, nullptr, 0);
}

// Round 5
// 134.621 us; speedup vs baseline: 14.3424x; 1.0593x over previous
//
#include <hip/hip_runtime.h>
#include <hip/hip_bf16.h>
#include <math.h>

typedef __attribute__((ext_vector_type(8))) short short8;
typedef __attribute__((ext_vector_type(4))) float f32x4;
typedef unsigned int uint;
typedef unsigned short ushort;

#define HWSZ 16384
#define PADW 130
#define SLAB (PADW*PADW*64)

__device__ __forceinline__ uint pk2bf(float a, float b) {
    union { __hip_bfloat162 h; uint u; } cv;
    cv.h = __float22bfloat162_rn(make_float2(a, b)); return cv.u;
}
__device__ __forceinline__ float bflo(uint u){ return __uint_as_float(u << 16); }
__device__ __forceinline__ float bfhi(uint u){ return __uint_as_float(u & 0xffff0000u); }

// ---------------------------------------------------------------------------
// bilinear combine of 4 corner short8's (8 bf16 channels) -> bf16 A-frag
// ---------------------------------------------------------------------------
__device__ __forceinline__ short8 combine4(short8 s0, short8 s1, short8 s2, short8 s3,
                                           float g0, float g1, float g2, float g3)
{
    uint4 u0 = *(uint4*)&s0, u1 = *(uint4*)&s1, u2 = *(uint4*)&s2, u3 = *(uint4*)&s3;
    float v0,v1,v2,v3,v4,v5,v6,v7;
    v0 = g0*bflo(u0.x); v1 = g0*bfhi(u0.x); v2 = g0*bflo(u0.y); v3 = g0*bfhi(u0.y);
    v4 = g0*bflo(u0.z); v5 = g0*bfhi(u0.z); v6 = g0*bflo(u0.w); v7 = g0*bfhi(u0.w);
    v0 = fmaf(g1,bflo(u1.x),v0); v1 = fmaf(g1,bfhi(u1.x),v1);
    v2 = fmaf(g1,bflo(u1.y),v2); v3 = fmaf(g1,bfhi(u1.y),v3);
    v4 = fmaf(g1,bflo(u1.z),v4); v5 = fmaf(g1,bfhi(u1.z),v5);
    v6 = fmaf(g1,bflo(u1.w),v6); v7 = fmaf(g1,bfhi(u1.w),v7);
    v0 = fmaf(g2,bflo(u2.x),v0); v1 = fmaf(g2,bfhi(u2.x),v1);
    v2 = fmaf(g2,bflo(u2.y),v2); v3 = fmaf(g2,bfhi(u2.y),v3);
    v4 = fmaf(g2,bflo(u2.z),v4); v5 = fmaf(g2,bfhi(u2.z),v5);
    v6 = fmaf(g2,bflo(u2.w),v6); v7 = fmaf(g2,bfhi(u2.w),v7);
    v0 = fmaf(g3,bflo(u3.x),v0); v1 = fmaf(g3,bfhi(u3.x),v1);
    v2 = fmaf(g3,bflo(u3.y),v2); v3 = fmaf(g3,bfhi(u3.y),v3);
    v4 = fmaf(g3,bflo(u3.z),v4); v5 = fmaf(g3,bfhi(u3.z),v5);
    v6 = fmaf(g3,bflo(u3.w),v6); v7 = fmaf(g3,bfhi(u3.w),v7);
    union { short8 s; uint u[4]; } r;
    r.u[0] = pk2bf(v0,v1); r.u[1] = pk2bf(v2,v3);
    r.u[2] = pk2bf(v4,v5); r.u[3] = pk2bf(v6,v7);
    return r.s;
}

// ---------------------------------------------------------------------------
// prep_x: blocks [0,128): NCHW fp32 -> padded NHWC bf16 (2-ch packed writes)
//         blocks [128,1160): zero borders of xt and y1t (all 4 batches)
// ---------------------------------------------------------------------------
__global__ __launch_bounds__(256, 2) void prep_x(
    const float* __restrict__ x, ushort* __restrict__ xtt, ushort* __restrict__ y1t)
{
    int t = threadIdx.x, l = t & 63, wv = t >> 6;
    if (blockIdx.x < 128) {
        int c2 = l & 31, ps = l >> 5;
        int pix0w = blockIdx.x * 512 + wv * 128;
        int bq = pix0w >> 14;
        const float* xp0 = x + ((size_t)(bq * 64 + c2 * 2)) * HWSZ;
        ushort* xw = xtt + (size_t)bq * SLAB;
        #pragma unroll 8
        for (int p = 0; p < 64; ++p) {
            int pxi = (pix0w + p * 2 + ps) & (HWSZ - 1);
            int i = pxi >> 7, j = pxi & 127;
            uint u = pk2bf(xp0[pxi], xp0[pxi + HWSZ]);
            *(uint*)(xw + ((i + 1) * PADW + (j + 1)) * 64 + c2 * 2) = u;
        }
    } else {
        int idx = (blockIdx.x - 128) * 256 + t;
        if (idx >= 264192) return;
        ushort* buf = (idx >= 132096) ? y1t : xtt;
        int e_all = idx % 132096;
        int bq = e_all / 33024, e = e_all % 33024;
        int i, j, c;
        if (e < 8320)       { i = 0;   j = e >> 6; c = e & 63; }
        else if (e < 16640) { int e2 = e - 8320; i = 129; j = e2 >> 6; c = e2 & 63; }
        else                { int e2 = e - 16640; c = e2 & 63;
                              i = (e2 >> 7) + 1; j = ((e2 >> 6) & 1) ? 129 : 0; }
        buf[(size_t)bq * SLAB + (i * PADW + j) * 64 + c] = 0;
    }
}

// ---------------------------------------------------------------------------
// prep_w: all four fragment-major weight buffers in one dispatch.
// wdf: [(tap*8 + kc*4 + nt)*512 + l*8 + j] = w_c[oc][c][tap],
//      c = kc*32+(l>>4)*8+j, oc = nt*16+(l&15)
// wof: [(tap*4 + kc*2 + nt)*512 + l*8 + j], ch = nt*16+(l&15) (27 padded to 32)
// NOTE: layer split by explicit subtraction — 36864/18432 are NOT powers of 2,
// so "& (N-1)" does not work (that was round 4's bug).
// ---------------------------------------------------------------------------
__global__ void prep_w(
    const float* __restrict__ wc1, const float* __restrict__ wp1, const float* __restrict__ wm1,
    const float* __restrict__ wc2, const float* __restrict__ wp2, const float* __restrict__ wm2,
    ushort* __restrict__ wdf1, ushort* __restrict__ wof1,
    ushort* __restrict__ wdf2, ushort* __restrict__ wof2)
{
    int idx0 = blockIdx.x * 256 + threadIdx.x;
    union { __hip_bfloat16 h; ushort u; } cv;
    if (idx0 < 73728) {
        int lay = idx0 >= 36864;
        int idx = idx0 - lay * 36864;
        const float* wc = lay ? wc2 : wc1;
        ushort* dst = lay ? wdf2 : wdf1;
        int j = idx & 7, l = (idx >> 3) & 63;
        int nt = (idx >> 9) & 3, kc = (idx >> 11) & 1, tap = idx >> 12;
        int c  = kc * 32 + (l >> 4) * 8 + j;
        int oc = nt * 16 + (l & 15);
        cv.h = __float2bfloat16(wc[(oc * 64 + c) * 9 + tap]);
        dst[idx] = cv.u;
    } else if (idx0 < 110592) {
        int r = idx0 - 73728;
        int lay = r >= 18432;
        int idx = r - lay * 18432;
        const float* wp = lay ? wp2 : wp1;
        const float* wm = lay ? wm2 : wm1;
        ushort* dst = lay ? wof2 : wof1;
        int j = idx & 7, l = (idx >> 3) & 63;
        int nt = (idx >> 9) & 1, kc = (idx >> 10) & 1, tap = idx >> 11;
        int c  = kc * 32 + (l >> 4) * 8 + j;
        int ch = nt * 16 + (l & 15);
        float v = 0.f;
        if (ch < 18)      v = wp[(ch * 64 + c) * 9 + tap];
        else if (ch < 27) v = wm[((ch - 18) * 64 + c) * 9 + tap];
        cv.h = __float2bfloat16(v);
        dst[idx] = cv.u;
    }
}

// ---------------------------------------------------------------------------
// Fused modulated-deformable-conv layer. 256 thr / 4 waves / 64 px (half row).
// Per wave (16 px, wave-private, barrier-free main path):
//  phase 1: offset/mask 3x3 conv via direct-load MFMA -> bias/sigmoid ->
//           wave-private LDS omW[27][16]
//  phase 2/3: per tap: coords (per lane, px=l&15), 8x b128 reg-gather,
//           VALU bilinear combine -> bf16 A-frags -> 8 MFMA (N=64)
//  mode 1: relu -> padded NHWC bf16 y1t (LDS transpose, 2 barriers)
//  mode 0: +residual -> NCHW fp32 out (direct stores, 0 barriers)
// ---------------------------------------------------------------------------
__global__ __launch_bounds__(256, 4) void fused(
    const ushort* __restrict__ xt, const ushort* __restrict__ wof,
    const float* __restrict__ bp, const float* __restrict__ bm,
    const ushort* __restrict__ wdf, const float* __restrict__ xres,
    float* __restrict__ outn, ushort* __restrict__ y1t, int mode)
{
    __shared__ __align__(16) char sm[16384];
    const int t = threadIdx.x, l = t & 63, wv = t >> 6;
    const int pix0 = blockIdx.x * 64;
    const int bb = pix0 >> 14, pxb = pix0 & (HWSZ - 1);
    const int irow = pxb >> 7;
    const int j0 = (pxb & 127) + wv * 16;      // wave's first pixel column
    const int px = l & 15, ck = l >> 4;        // lane's pixel / channel-chunk
    const ushort* xb = xt + (size_t)bb * SLAB;

    // ---------- phase 1: offset/mask conv ----------
    f32x4 z4 = {0.f, 0.f, 0.f, 0.f};
    f32x4 oa0 = z4, oa1 = z4;
    #pragma unroll
    for (int tap = 0; tap < 9; ++tap) {
        int ti = tap / 3, tj = tap - ti * 3;
        const ushort* ap = xb + ((irow + ti) * PADW + j0 + px + tj) * 64 + ck * 8;
        short8 a0 = *(const short8*)ap;
        short8 a1 = *(const short8*)(ap + 32);
        short8 b00 = *(const short8*)(wof + (tap * 4 + 0) * 512 + l * 8);
        short8 b01 = *(const short8*)(wof + (tap * 4 + 1) * 512 + l * 8);
        short8 b10 = *(const short8*)(wof + (tap * 4 + 2) * 512 + l * 8);
        short8 b11 = *(const short8*)(wof + (tap * 4 + 3) * 512 + l * 8);
        oa0 = __builtin_amdgcn_mfma_f32_16x16x32_bf16(a0, b00, oa0, 0, 0, 0);
        oa1 = __builtin_amdgcn_mfma_f32_16x16x32_bf16(a0, b01, oa1, 0, 0, 0);
        oa0 = __builtin_amdgcn_mfma_f32_16x16x32_bf16(a1, b10, oa0, 0, 0, 0);
        oa1 = __builtin_amdgcn_mfma_f32_16x16x32_bf16(a1, b11, oa1, 0, 0, 0);
    }
    float* omW = ((float*)sm) + wv * 544;      // [27][16] stride 17
    #pragma unroll
    for (int nt = 0; nt < 2; ++nt) {
        f32x4 oa = nt ? oa1 : oa0;
        int ch = nt * 16 + px;                 // D-layout: col(l&15)=ch
        #pragma unroll
        for (int r = 0; r < 4; ++r) {
            int pxl = ck * 4 + r;              // D-layout: row=pixel
            if (ch < 27) {
                float v = oa[r] + ((ch < 18) ? bp[ch] : bm[ch - 18]);
                if (ch >= 18) v = 1.f / (1.f + __expf(-v));
                omW[ch * 17 + pxl] = v;
            }
        }
    }

    // ---------- phase 2/3: deformable sampling + contraction ----------
    f32x4 acc0 = z4, acc1 = z4, acc2 = z4, acc3 = z4;
    const char* pbase = (const char*)xb + ck * 16;
    const int jcol = j0 + px;
    #pragma unroll
    for (int n = 0; n < 9; ++n) {
        int di = n / 3, dj = n - di * 3;
        float offx = omW[n * 17 + px];
        float offy = omW[(9 + n) * 17 + px];
        float mv   = omW[(18 + n) * 17 + px];
        float pxf = (float)(irow + di) + offx;
        float pyf = (float)(jcol + dj) + offy;
        float fx = floorf(pxf), fy = floorf(pyf);
        float qltx = fminf(fmaxf(fx,       0.f), 129.f);
        float qlty = fminf(fmaxf(fy,       0.f), 129.f);
        float qrbx = fminf(fmaxf(fx + 1.f, 0.f), 129.f);
        float qrby = fminf(fmaxf(fy + 1.f, 0.f), 129.f);
        float pxc  = fminf(fmaxf(pxf,      0.f), 129.f);
        float pyc  = fminf(fmaxf(pyf,      0.f), 129.f);
        float glt = (1.f + (qltx - pxc)) * (1.f + (qlty - pyc));
        float grb = (1.f - (qrbx - pxc)) * (1.f - (qrby - pyc));
        float glb = (1.f + (qltx - pxc)) * (1.f - (qrby - pyc));
        float grt = (1.f - (qrbx - pxc)) * (1.f + (qlty - pyc));
        int ltx = (int)qltx, lty = (int)qlty, rbx = (int)qrbx, rby = (int)qrby;
        float g0 = glt * mv, g1 = grb * mv, g2 = glb * mv, g3 = grt * mv;
        int b_lt = (ltx * PADW + lty) * 128;
        int b_rb = (rbx * PADW + rby) * 128;
        int b_lb = (ltx * PADW + rby) * 128;
        int b_rt = (rbx * PADW + lty) * 128;

        short8 dlt0 = *(const short8*)(pbase + b_lt);
        short8 dlt1 = *(const short8*)(pbase + b_lt + 64);
        short8 drb0 = *(const short8*)(pbase + b_rb);
        short8 drb1 = *(const short8*)(pbase + b_rb + 64);
        short8 dlb0 = *(const short8*)(pbase + b_lb);
        short8 dlb1 = *(const short8*)(pbase + b_lb + 64);
        short8 drt0 = *(const short8*)(pbase + b_rt);
        short8 drt1 = *(const short8*)(pbase + b_rt + 64);

        short8 a0 = combine4(dlt0, drb0, dlb0, drt0, g0, g1, g2, g3);
        short8 a1 = combine4(dlt1, drb1, dlb1, drt1, g0, g1, g2, g3);

        const ushort* wbase = wdf + (size_t)n * 4096 + l * 8;
        short8 w00 = *(const short8*)(wbase);
        short8 w01 = *(const short8*)(wbase + 512);
        short8 w02 = *(const short8*)(wbase + 1024);
        short8 w03 = *(const short8*)(wbase + 1536);
        acc0 = __builtin_amdgcn_mfma_f32_16x16x32_bf16(a0, w00, acc0, 0, 0, 0);
        acc1 = __builtin_amdgcn_mfma_f32_16x16x32_bf16(a0, w01, acc1, 0, 0, 0);
        acc2 = __builtin_amdgcn_mfma_f32_16x16x32_bf16(a0, w02, acc2, 0, 0, 0);
        acc3 = __builtin_amdgcn_mfma_f32_16x16x32_bf16(a0, w03, acc3, 0, 0, 0);
        short8 w10 = *(const short8*)(wbase + 2048);
        short8 w11 = *(const short8*)(wbase + 2560);
        short8 w12 = *(const short8*)(wbase + 3072);
        short8 w13 = *(const short8*)(wbase + 3584);
        acc0 = __builtin_amdgcn_mfma_f32_16x16x32_bf16(a1, w10, acc0, 0, 0, 0);
        acc1 = __builtin_amdgcn_mfma_f32_16x16x32_bf16(a1, w11, acc1, 0, 0, 0);
        acc2 = __builtin_amdgcn_mfma_f32_16x16x32_bf16(a1, w12, acc2, 0, 0, 0);
        acc3 = __builtin_amdgcn_mfma_f32_16x16x32_bf16(a1, w13, acc3, 0, 0, 0);
    }

    // ---------- epilogue ----------
    if (mode == 0) {
        // +residual -> NCHW fp32, direct float4 stores (4 consecutive px per lane)
        int pxi0 = pxb + wv * 16 + ck * 4;
        f32x4 av[4] = {acc0, acc1, acc2, acc3};
        #pragma unroll
        for (int nt = 0; nt < 4; ++nt) {
            int oc = nt * 16 + px;
            size_t o = ((size_t)(bb * 64 + oc)) * HWSZ + pxi0;
            float4 rsd = *(const float4*)(xres + o);
            float4 vv;
            vv.x = av[nt][0] + rsd.x; vv.y = av[nt][1] + rsd.y;
            vv.z = av[nt][2] + rsd.z; vv.w = av[nt][3] + rsd.w;
            *(float4*)(outn + o) = vv;
        }
    } else {
        // relu -> padded NHWC bf16 via LDS transpose
        __syncthreads();
        float* T = (float*)sm;
        f32x4 av[4] = {acc0, acc1, acc2, acc3};
        #pragma unroll
        for (int nt = 0; nt < 4; ++nt) {
            int oc = nt * 16 + px;
            #pragma unroll
            for (int r = 0; r < 4; ++r) {
                int pxl = wv * 16 + ck * 4 + r;
                T[oc * 64 + (pxl ^ (oc & 31))] = fmaxf(av[nt][r], 0.f);
            }
        }
        __syncthreads();
        int pxx = t & 63, cg = t >> 6;
        int pxi = pxb + pxx;
        int i = pxi >> 7, j = pxi & 127;
        ushort* dst = y1t + (size_t)bb * SLAB + ((i + 1) * PADW + (j + 1)) * 64 + cg * 16;
        uint w[8];
        #pragma unroll
        for (int k2 = 0; k2 < 8; ++k2) {
            int oc0 = cg * 16 + k2 * 2;
            float a0 = T[oc0 * 64 + (pxx ^ (oc0 & 31))];
            float a1 = T[(oc0 + 1) * 64 + (pxx ^ ((oc0 + 1) & 31))];
            w[k2] = pk2bf(a0, a1);
        }
        *(uint4*)dst = make_uint4(w[0], w[1], w[2], w[3]);
        *(uint4*)(dst + 8) = make_uint4(w[4], w[5], w[6], w[7]);
    }
}

// ---------------------------------------------------------------------------
extern "C" void kernel_launch(void* const* d_in, const int* in_sizes, int n_in,
                              void* d_out, int out_size, void* d_ws, size_t ws_size,
                              hipStream_t stream)
{
    const float* x      = (const float*)d_in[0];
    const float* d1_w_p = (const float*)d_in[1];
    const float* d1_b_p = (const float*)d_in[2];
    const float* d1_w_m = (const float*)d_in[3];
    const float* d1_b_m = (const float*)d_in[4];
    const float* d1_w_c = (const float*)d_in[5];
    const float* d2_w_p = (const float*)d_in[6];
    const float* d2_b_p = (const float*)d_in[7];
    const float* d2_w_m = (const float*)d_in[8];
    const float* d2_b_m = (const float*)d_in[9];
    const float* d2_w_c = (const float*)d_in[10];
    float* out = (float*)d_out;

    char* ws = (char*)d_ws;
    ushort* xtt  = (ushort*)(ws);               //  8,652,800 B padded NHWC bf16 x
    ushort* y1t  = (ushort*)(ws + 8652800);     //  8,652,800 B padded NHWC bf16 y1
    ushort* wdf1 = (ushort*)(ws + 17305600);    //     73,728 B
    ushort* wof1 = (ushort*)(ws + 17379328);    //     36,864 B
    ushort* wdf2 = (ushort*)(ws + 17416192);    //     73,728 B
    ushort* wof2 = (ushort*)(ws + 17489920);    //     36,864 B

    prep_w<<<432, 256, 0, stream>>>(d1_w_c, d1_w_p, d1_w_m, d2_w_c, d2_w_p, d2_w_m,
                                    wdf1, wof1, wdf2, wof2);
    prep_x<<<1160, 256, 0, stream>>>(x, xtt, y1t);

    fused<<<1024, 256, 0, stream>>>(xtt, wof1, d1_b_p, d1_b_m, wdf1,
                                    nullptr, nullptr, y1t, 1);
    fused<<<1024, 256, 0, stream>>>(y1t, wof2, d2_b_p, d2_b_m, wdf2,
                                    x, out, nullptr, 0);
}